// Round 7
// baseline (149.182 us; speedup 1.0000x reference)
//
#include <hip/hip_runtime.h>
#include <hip/hip_bf16.h>

// Problem: B=2, L=2048, D=1024, N=16  -> rows R = 4096, K = 1024
// y[r,d] = x[r,d] * softplus((x@W1^T)[r,d] + b1[d]) * s[r]
// s[r]   = sum_n (x@W2^T + b2)[r,n] * (x@W3^T + b3)[r,n]
// (dA * h0 == 0, so A is unused.)

#define ROWS 4096
#define KDIM 1024

typedef __attribute__((ext_vector_type(8))) __bf16 bf16x8;
typedef __attribute__((ext_vector_type(4))) float f32x4;

// ---------- helpers ----------
__device__ __forceinline__ unsigned short f2bf_rne(float f) {
    unsigned u = __float_as_uint(f);
    u += 0x7FFFu + ((u >> 16) & 1u);   // round-to-nearest-even
    return (unsigned short)(u >> 16);
}
__device__ __forceinline__ unsigned pack2(float lo, float hi) {
    return (unsigned)f2bf_rne(lo) | ((unsigned)f2bf_rne(hi) << 16);
}

// ---------- kernel 1: pure streaming fp32 -> bf16 (x, W1, W2, W3) ----------
// 2576 blocks x 256 thr x 8 elems = 5,275,648 elements exactly.
__global__ __launch_bounds__(256) void prep_kernel(
        const float* __restrict__ x,  const float* __restrict__ W1,
        const float* __restrict__ W2, const float* __restrict__ W3,
        unsigned short* __restrict__ xb, unsigned short* __restrict__ w1b,
        unsigned short* __restrict__ w2b, unsigned short* __restrict__ w3b) {
    const long long NX  = (long long)ROWS * KDIM;   // 4,194,304
    const long long NW1 = (long long)KDIM * KDIM;   // 1,048,576
    const long long NW  = 16LL * KDIM;              // 16,384
    long long i = ((long long)blockIdx.x * 256 + threadIdx.x) * 8;
    const float* src;
    unsigned short* dst;
    if (i < NX)                 { src = x  + i;                 dst = xb  + i; }
    else if (i < NX + NW1)      { src = W1 + (i - NX);          dst = w1b + (i - NX); }
    else if (i < NX + NW1 + NW) { src = W2 + (i - NX - NW1);    dst = w2b + (i - NX - NW1); }
    else                        { src = W3 + (i - NX - NW1 - NW); dst = w3b + (i - NX - NW1 - NW); }
    float4 a = *(const float4*)src;
    float4 b = *(const float4*)(src + 4);
    uint4 o;
    o.x = pack2(a.x, a.y); o.y = pack2(a.z, a.w);
    o.z = pack2(b.x, b.y); o.w = pack2(b.z, b.w);
    *(uint4*)dst = o;
}

// ---------- kernel 2: s[r] via MFMA over bf16 inputs (unchanged) ----------
__global__ __launch_bounds__(256) void s_kernel(
        const unsigned short* __restrict__ xb,
        const unsigned short* __restrict__ w2b, const float* __restrict__ b2,
        const unsigned short* __restrict__ w3b, const float* __restrict__ b3,
        float* __restrict__ s) {
    __shared__ f32x4 redB[4][64];
    __shared__ f32x4 redC[4][64];
    const int t = threadIdx.x;
    const int lane = t & 63;
    const int wv = t >> 6;
    const int m = lane & 15;              // A row-within-16 / B n index
    const int kq = (lane >> 4) * 8;       // k offset within 32-step
    const int r0 = blockIdx.x * 16;
    const int kbase = wv * 256;

    f32x4 accB = (f32x4){0.f, 0.f, 0.f, 0.f};
    f32x4 accC = (f32x4){0.f, 0.f, 0.f, 0.f};
    const unsigned short* xr  = xb  + (size_t)(r0 + m) * KDIM + kbase + kq;
    const unsigned short* w2r = w2b + (size_t)m * KDIM + kbase + kq;
    const unsigned short* w3r = w3b + (size_t)m * KDIM + kbase + kq;
#pragma unroll
    for (int ks = 0; ks < 256; ks += 32) {
        bf16x8 af  = *(const bf16x8*)(xr  + ks);
        bf16x8 b2f = *(const bf16x8*)(w2r + ks);
        bf16x8 b3f = *(const bf16x8*)(w3r + ks);
        accB = __builtin_amdgcn_mfma_f32_16x16x32_bf16(af, b2f, accB, 0, 0, 0);
        accC = __builtin_amdgcn_mfma_f32_16x16x32_bf16(af, b3f, accC, 0, 0, 0);
    }
    redB[wv][lane] = accB;
    redC[wv][lane] = accC;
    __syncthreads();
    if (wv == 0) {
        f32x4 tB = redB[0][lane], tC = redC[0][lane];
#pragma unroll
        for (int w = 1; w < 4; ++w) { tB += redB[w][lane]; tC += redC[w][lane]; }
        // C/D layout: lane holds D[row=(lane>>4)*4+r][col = n = lane&15]
        const float b2n = b2[m], b3n = b3[m];
        const int q4 = (lane >> 4) * 4;
#pragma unroll
        for (int r = 0; r < 4; ++r) {
            float p = (tB[r] + b2n) * (tC[r] + b3n);
            p += __shfl_xor(p, 1, 64);
            p += __shfl_xor(p, 2, 64);
            p += __shfl_xor(p, 4, 64);
            p += __shfl_xor(p, 8, 64);
            if (m == 0) s[r0 + q4 + r] = p;
        }
    }
}

// ---------- kernel 4 helpers: fragment load macros ----------
#define LOAD_A(dst, k)                                                        \
    _Pragma("unroll")                                                         \
    for (int i = 0; i < 4; ++i)                                               \
        dst[i] = *(const bf16x8*)(pa + (size_t)i * 16 * KDIM + (k));
#define LOAD_B(dst, k)                                                        \
    _Pragma("unroll")                                                         \
    for (int i = 0; i < 2; ++i)                                               \
        dst[i] = *(const bf16x8*)(pb + (size_t)i * 16 * KDIM + (k));
#define MFMA_STEP(af, bfr)                                                    \
    _Pragma("unroll")                                                         \
    for (int mi = 0; mi < 4; ++mi)                                            \
        _Pragma("unroll")                                                     \
        for (int ni = 0; ni < 2; ++ni)                                        \
            acc[mi][ni] = __builtin_amdgcn_mfma_f32_16x16x32_bf16(            \
                af[mi], bfr[ni], acc[mi][ni], 0, 0, 0);

// ---------- kernel 3: LDS-free streaming GEMM, EXPLICIT 2-stage reg pipeline ----------
// R6's flat loop let the compiler pick a 48-VGPR register-minimal schedule with
// zero load/compute overlap (MfmaUtil 5%). v4 forces a software pipeline with
// explicit double buffers a0/b0, a1/b1: prefetched frags are live across the
// MFMA block, so the compiler must keep them allocated and can only insert
// partial vmcnt waits. Still NO barriers. 512 blocks XCD-swizzled (per-XCD
// working set 3 MB = L2-resident); 4 waves in 2x2, wave tile 64x32.
__global__ __launch_bounds__(256, 2) void gemm_fused(
        const unsigned short* __restrict__ xb,   // [4096][1024] bf16
        const unsigned short* __restrict__ w1b,  // [1024][1024] bf16 (row e, col k)
        const float* __restrict__ b1,
        const float* __restrict__ x,             // fp32 original
        const float* __restrict__ s,
        float* __restrict__ y) {
    const int bid = blockIdx.x;
    const int xcd = bid & 7;
    const int l = bid >> 3;                   // 0..63
    const int row0 = (xcd * 4 + (l >> 4)) * 128;
    const int col0 = (l & 15) * 64;

    const int t = threadIdx.x;
    const int lane = t & 63;
    const int wv = t >> 6;          // 0..3
    const int wm = wv >> 1;         // wave row 0..1 (64 rows each)
    const int wn = wv & 1;          // wave col 0..1 (32 cols each)
    const int m = lane & 15;
    const int kq = (lane >> 4) * 8;

    f32x4 acc[4][2];
#pragma unroll
    for (int mi = 0; mi < 4; ++mi)
#pragma unroll
        for (int ni = 0; ni < 2; ++ni)
            acc[mi][ni] = (f32x4){0.f, 0.f, 0.f, 0.f};

    // frag base pointers: A rows row0+wm*64+mi*16+m ; B rows col0+wn*32+ni*16+m
    const unsigned short* pa = xb  + (size_t)(row0 + wm * 64 + m) * KDIM + kq;
    const unsigned short* pb = w1b + (size_t)(col0 + wn * 32 + m) * KDIM + kq;

    bf16x8 a0[4], b0[2], a1[4], b1v[2];
    LOAD_A(a0, 0)
    LOAD_B(b0, 0)
    // 16 outer iters x 64 K each; prefetch half-iter k+32 before computing k.
#pragma unroll 4
    for (int k0 = 0; k0 < KDIM; k0 += 64) {
        LOAD_A(a1, k0 + 32)
        LOAD_B(b1v, k0 + 32)
        MFMA_STEP(a0, b0)
        if (k0 + 64 < KDIM) {
            LOAD_A(a0, k0 + 64)
            LOAD_B(b0, k0 + 64)
        }
        MFMA_STEP(a1, b1v)
    }

    // epilogue: y = softplus(acc + b1) * x * s ; D layout: col=lane&15, row=(lane>>4)*4+reg
    const int q4 = (lane >> 4) * 4;
#pragma unroll
    for (int mi = 0; mi < 4; ++mi) {
        const int rbase = row0 + wm * 64 + mi * 16 + q4;
        float4 s4 = *(const float4*)&s[rbase];
        const float* sp4 = (const float*)&s4;
#pragma unroll
        for (int ni = 0; ni < 2; ++ni) {
            const int c = col0 + wn * 32 + ni * 16 + m;
            const float bias = b1[c];
#pragma unroll
            for (int r = 0; r < 4; ++r) {
                float z = acc[mi][ni][r] + bias;
                float sp = fmaxf(z, 0.f) + log1pf(__expf(-fabsf(z)));
                size_t idx = (size_t)(rbase + r) * KDIM + c;
                y[idx] = sp * x[idx] * sp4[r];
            }
        }
    }
}

// ---------- launch ----------
extern "C" void kernel_launch(void* const* d_in, const int* in_sizes, int n_in,
                              void* d_out, int out_size, void* d_ws, size_t ws_size,
                              hipStream_t stream) {
    const float* x  = (const float*)d_in[0];
    const float* W1 = (const float*)d_in[1];
    const float* b1 = (const float*)d_in[2];
    const float* W2 = (const float*)d_in[3];
    const float* b2 = (const float*)d_in[4];
    const float* W3 = (const float*)d_in[5];
    const float* b3 = (const float*)d_in[6];
    // d_in[7] = A : unused (multiplied by h0 == 0 in the reference)
    float* y = (float*)d_out;

    unsigned short* xb  = (unsigned short*)d_ws;              // 4096*1024 bf16 = 8 MB
    unsigned short* w1b = xb  + (size_t)ROWS * KDIM;          // 1024*1024 bf16 = 2 MB
    unsigned short* w2b = w1b + (size_t)KDIM * KDIM;          // 16*1024 bf16 = 32 KB
    unsigned short* w3b = w2b + (size_t)16 * KDIM;            // 16*1024 bf16 = 32 KB
    float* s = (float*)(w3b + (size_t)16 * KDIM);             // 4096 f32

    prep_kernel<<<dim3(2576), dim3(256), 0, stream>>>(x, W1, W2, W3, xb, w1b, w2b, w3b);
    s_kernel<<<dim3(256), dim3(256), 0, stream>>>(xb, w2b, b2, w3b, b3, s);
    gemm_fused<<<dim3(512), dim3(256), 0, stream>>>(xb, w1b, b1, x, s, y);
}

// Round 8
// 107.662 us; speedup vs baseline: 1.3857x; 1.3857x over previous
//
#include <hip/hip_runtime.h>
#include <hip/hip_bf16.h>

// Problem: B=2, L=2048, D=1024, N=16  -> rows R = 4096, K = 1024
// y[r,d] = x[r,d] * softplus((x@W1^T)[r,d] + b1[d]) * s[r]
// s[r]   = sum_n (x@W2^T + b2)[r,n] * (x@W3^T + b3)[r,n]
// (dA * h0 == 0, so A is unused.)

#define ROWS 4096
#define KDIM 1024

typedef __attribute__((ext_vector_type(8))) __bf16 bf16x8;
typedef __attribute__((ext_vector_type(4))) float f32x4;

// ---------- helpers ----------
__device__ __forceinline__ unsigned short f2bf_rne(float f) {
    unsigned u = __float_as_uint(f);
    u += 0x7FFFu + ((u >> 16) & 1u);   // round-to-nearest-even
    return (unsigned short)(u >> 16);
}
__device__ __forceinline__ unsigned pack2(float lo, float hi) {
    return (unsigned)f2bf_rne(lo) | ((unsigned)f2bf_rne(hi) << 16);
}
__device__ __forceinline__ void async16(const void* g, void* l) {
    __builtin_amdgcn_global_load_lds(
        (const __attribute__((address_space(1))) void*)g,
        (__attribute__((address_space(3))) void*)l, 16, 0, 0);
}
__device__ __forceinline__ float bf2f(unsigned short h) {
    return __uint_as_float((unsigned)h << 16);
}

// ---------- kernel 1: pure streaming fp32 -> bf16 (x, W1, W2, W3) ----------
// 2576 blocks x 256 thr x 8 elems = 5,275,648 elements exactly.
__global__ __launch_bounds__(256) void prep_kernel(
        const float* __restrict__ x,  const float* __restrict__ W1,
        const float* __restrict__ W2, const float* __restrict__ W3,
        unsigned short* __restrict__ xb, unsigned short* __restrict__ w1b,
        unsigned short* __restrict__ w2b, unsigned short* __restrict__ w3b) {
    const long long NX  = (long long)ROWS * KDIM;   // 4,194,304
    const long long NW1 = (long long)KDIM * KDIM;   // 1,048,576
    const long long NW  = 16LL * KDIM;              // 16,384
    long long i = ((long long)blockIdx.x * 256 + threadIdx.x) * 8;
    const float* src;
    unsigned short* dst;
    if (i < NX)                 { src = x  + i;                 dst = xb  + i; }
    else if (i < NX + NW1)      { src = W1 + (i - NX);          dst = w1b + (i - NX); }
    else if (i < NX + NW1 + NW) { src = W2 + (i - NX - NW1);    dst = w2b + (i - NX - NW1); }
    else                        { src = W3 + (i - NX - NW1 - NW); dst = w3b + (i - NX - NW1 - NW); }
    float4 a = *(const float4*)src;
    float4 b = *(const float4*)(src + 4);
    uint4 o;
    o.x = pack2(a.x, a.y); o.y = pack2(a.z, a.w);
    o.z = pack2(b.x, b.y); o.w = pack2(b.z, b.w);
    *(uint4*)dst = o;
}

// ---------- kernel 2: s[r] via MFMA over bf16 inputs (unchanged) ----------
__global__ __launch_bounds__(256) void s_kernel(
        const unsigned short* __restrict__ xb,
        const unsigned short* __restrict__ w2b, const float* __restrict__ b2,
        const unsigned short* __restrict__ w3b, const float* __restrict__ b3,
        float* __restrict__ s) {
    __shared__ f32x4 redB[4][64];
    __shared__ f32x4 redC[4][64];
    const int t = threadIdx.x;
    const int lane = t & 63;
    const int wv = t >> 6;
    const int m = lane & 15;              // A row-within-16 / B n index
    const int kq = (lane >> 4) * 8;       // k offset within 32-step
    const int r0 = blockIdx.x * 16;
    const int kbase = wv * 256;

    f32x4 accB = (f32x4){0.f, 0.f, 0.f, 0.f};
    f32x4 accC = (f32x4){0.f, 0.f, 0.f, 0.f};
    const unsigned short* xr  = xb  + (size_t)(r0 + m) * KDIM + kbase + kq;
    const unsigned short* w2r = w2b + (size_t)m * KDIM + kbase + kq;
    const unsigned short* w3r = w3b + (size_t)m * KDIM + kbase + kq;
#pragma unroll
    for (int ks = 0; ks < 256; ks += 32) {
        bf16x8 af  = *(const bf16x8*)(xr  + ks);
        bf16x8 b2f = *(const bf16x8*)(w2r + ks);
        bf16x8 b3f = *(const bf16x8*)(w3r + ks);
        accB = __builtin_amdgcn_mfma_f32_16x16x32_bf16(af, b2f, accB, 0, 0, 0);
        accC = __builtin_amdgcn_mfma_f32_16x16x32_bf16(af, b3f, accC, 0, 0, 0);
    }
    redB[wv][lane] = accB;
    redC[wv][lane] = accC;
    __syncthreads();
    if (wv == 0) {
        f32x4 tB = redB[0][lane], tC = redC[0][lane];
#pragma unroll
        for (int w = 1; w < 4; ++w) { tB += redB[w][lane]; tC += redC[w][lane]; }
        const float b2n = b2[m], b3n = b3[m];
        const int q4 = (lane >> 4) * 4;
#pragma unroll
        for (int r = 0; r < 4; ++r) {
            float p = (tB[r] + b2n) * (tC[r] + b3n);
            p += __shfl_xor(p, 1, 64);
            p += __shfl_xor(p, 2, 64);
            p += __shfl_xor(p, 4, 64);
            p += __shfl_xor(p, 8, 64);
            if (m == 0) s[r0 + q4 + r] = p;
        }
    }
}

// ---------- kernel 3: LDS double-buffered MFMA GEMM, 1 barrier/iter ----------
// BM=128, BN=64, BK=64. 512 blocks XCD-swizzled, 2 blocks/CU, 48 KB LDS.
// Per iter: stage tile k+1 into buf^1 (async global_load_lds, 6x16B/thread),
// compute tile k from buf (12 ds_read_b128 + 16 MFMA per wave), ONE sync.
// The vmcnt(0) drain at the barrier waits on loads issued a compute-phase
// earlier -> overlap the 2-barrier m97 structure can't express.
// LDS columns XOR-swizzled at global-address level (global_load_lds's LDS
// side is lane-fixed): LDS[row][q] holds global col-octet (q ^ (row&7)).
// ds_read then hits 8 distinct bank-quads (2-way alias = free) despite the
// 128 B row stride.
__global__ __launch_bounds__(256, 2) void gemm_fused(
        const unsigned short* __restrict__ xb,   // [4096][1024] bf16
        const unsigned short* __restrict__ w1b,  // [1024][1024] bf16 (row e, col k)
        const float* __restrict__ b1,
        const float* __restrict__ s,
        float* __restrict__ y) {
    __shared__ __align__(16) unsigned short As[2][128 * 64];  // 32 KB
    __shared__ __align__(16) unsigned short Bs[2][64 * 64];   // 16 KB

    const int bid = blockIdx.x;
    const int xcd = bid & 7;
    const int l = bid >> 3;                   // 0..63
    const int row0 = (xcd * 4 + (l >> 4)) * 128;
    const int col0 = (l & 15) * 64;

    const int t = threadIdx.x;
    const int lane = t & 63;
    const int wv = t >> 6;          // 0..3
    const int wm = wv >> 1;         // wave row 0..1 (64 rows each)
    const int wn = wv & 1;          // wave col 0..1 (32 cols each)
    const int m = lane & 15;
    const int q2 = lane >> 4;       // 0..3

    // staging lane mapping: instr j covers 8 rows x 64 cols (1 KB);
    // lane i -> row (i>>3), col-octet swizzled: (i&7) ^ (i>>3)
    const int srow = lane >> 3;                       // 0..7
    const int scol = ((lane & 7) ^ srow) * 8;         // swizzled col (elems)

    f32x4 acc[4][2];
#pragma unroll
    for (int mi = 0; mi < 4; ++mi)
#pragma unroll
        for (int ni = 0; ni < 2; ++ni)
            acc[mi][ni] = (f32x4){0.f, 0.f, 0.f, 0.f};

#define STAGE(b, k0)                                                          \
    {                                                                         \
        _Pragma("unroll")                                                     \
        for (int j = wv * 4; j < wv * 4 + 4; ++j)                             \
            async16(xb + (size_t)(row0 + j * 8 + srow) * KDIM + (k0) + scol,  \
                    &As[b][j * 512]);                                         \
        _Pragma("unroll")                                                     \
        for (int j = wv * 2; j < wv * 2 + 2; ++j)                             \
            async16(w1b + (size_t)(col0 + j * 8 + srow) * KDIM + (k0) + scol, \
                    &Bs[b][j * 512]);                                         \
    }

    STAGE(0, 0)
    __syncthreads();

#pragma unroll 2
    for (int it = 0; it < 16; ++it) {
        const int cur = it & 1;
        if (it + 1 < 16) STAGE(cur ^ 1, (it + 1) * 64)
#pragma unroll
        for (int ks = 0; ks < 64; ks += 32) {
            bf16x8 af[4], bfr[2];
#pragma unroll
            for (int mi = 0; mi < 4; ++mi) {
                const int row = wm * 64 + mi * 16 + m;
                const int ql = ((ks >> 3) + q2) ^ (m & 7);
                af[mi] = *(const bf16x8*)&As[cur][row * 64 + ql * 8];
            }
#pragma unroll
            for (int ni = 0; ni < 2; ++ni) {
                const int row = wn * 32 + ni * 16 + m;
                const int ql = ((ks >> 3) + q2) ^ (m & 7);
                bfr[ni] = *(const bf16x8*)&Bs[cur][row * 64 + ql * 8];
            }
#pragma unroll
            for (int mi = 0; mi < 4; ++mi)
#pragma unroll
                for (int ni = 0; ni < 2; ++ni)
                    acc[mi][ni] = __builtin_amdgcn_mfma_f32_16x16x32_bf16(
                        af[mi], bfr[ni], acc[mi][ni], 0, 0, 0);
        }
        __syncthreads();
    }

    // epilogue: y = softplus(acc + b1) * x * s ; D layout: col=lane&15, row=q2*4+reg
    // x read as bf16 from xb (L2-hot: these rows were just staged).
    const int q4 = q2 * 4;
#pragma unroll
    for (int mi = 0; mi < 4; ++mi) {
        const int rbase = row0 + wm * 64 + mi * 16 + q4;
        float4 s4 = *(const float4*)&s[rbase];
        const float* sp4 = (const float*)&s4;
#pragma unroll
        for (int ni = 0; ni < 2; ++ni) {
            const int c = col0 + wn * 32 + ni * 16 + m;
            const float bias = b1[c];
#pragma unroll
            for (int r = 0; r < 4; ++r) {
                float z = acc[mi][ni][r] + bias;
                float sp = fmaxf(z, 0.f) + __logf(1.f + __expf(-fabsf(z)));
                size_t idx = (size_t)(rbase + r) * KDIM + c;
                y[idx] = sp * bf2f(xb[idx]) * sp4[r];
            }
        }
    }
#undef STAGE
}

// ---------- launch ----------
extern "C" void kernel_launch(void* const* d_in, const int* in_sizes, int n_in,
                              void* d_out, int out_size, void* d_ws, size_t ws_size,
                              hipStream_t stream) {
    const float* x  = (const float*)d_in[0];
    const float* W1 = (const float*)d_in[1];
    const float* b1 = (const float*)d_in[2];
    const float* W2 = (const float*)d_in[3];
    const float* b2 = (const float*)d_in[4];
    const float* W3 = (const float*)d_in[5];
    const float* b3 = (const float*)d_in[6];
    // d_in[7] = A : unused (multiplied by h0 == 0 in the reference)
    float* y = (float*)d_out;

    unsigned short* xb  = (unsigned short*)d_ws;              // 4096*1024 bf16 = 8 MB
    unsigned short* w1b = xb  + (size_t)ROWS * KDIM;          // 1024*1024 bf16 = 2 MB
    unsigned short* w2b = w1b + (size_t)KDIM * KDIM;          // 16*1024 bf16 = 32 KB
    unsigned short* w3b = w2b + (size_t)16 * KDIM;            // 16*1024 bf16 = 32 KB
    float* s = (float*)(w3b + (size_t)16 * KDIM);             // 4096 f32

    prep_kernel<<<dim3(2576), dim3(256), 0, stream>>>(x, W1, W2, W3, xb, w1b, w2b, w3b);
    s_kernel<<<dim3(256), dim3(256), 0, stream>>>(xb, w2b, b2, w3b, b3, s);
    gemm_fused<<<dim3(512), dim3(256), 0, stream>>>(xb, w1b, b1, s, y);
}